// Round 1
// baseline (437.588 us; speedup 1.0000x reference)
//
#include <hip/hip_runtime.h>
#include <hip/hip_bf16.h>

// Problem constants (from reference): B=32, T=2048, C=1152, O=29.
// z[b,o] = ( (1/64)*dot(W[o,:], s[b,:]) - 2*T*sum(W[o,:]) + T*bias[o] ) / length[b]
// where s[b,c] = sum_t x[b,t,c].

#define PB 32
#define PT 2048
#define PC 1152
#define PO 29
#define TSPLIT 32           // T-parallel splits per batch
#define C4 (PC / 4)         // 288 float4 per row

// Kernel 1: s[b,c] = sum over a T-slab of x[b,t,c]; atomic-accumulate into ws.
// grid = (B, TSPLIT), block = 256. Threads cover c4 = tid (all) and c4 = 256+tid (tid<32).
__global__ __launch_bounds__(256) void sum_t_kernel(const float* __restrict__ x,
                                                    float* __restrict__ s) {
    const int b   = blockIdx.x;
    const int p   = blockIdx.y;
    const int tid = threadIdx.x;

    const float4* x4 = (const float4*)(x + (size_t)b * PT * PC);

    float4 acc0 = make_float4(0.f, 0.f, 0.f, 0.f);
    float4 acc1 = make_float4(0.f, 0.f, 0.f, 0.f);

    const int tBeg = p * (PT / TSPLIT);
    const int tEnd = tBeg + (PT / TSPLIT);

#pragma unroll 4
    for (int t = tBeg; t < tEnd; ++t) {
        const float4* row = x4 + (size_t)t * C4;
        float4 v = row[tid];
        acc0.x += v.x; acc0.y += v.y; acc0.z += v.z; acc0.w += v.w;
        if (tid < C4 - 256) {                 // 32 extra columns
            float4 v2 = row[256 + tid];
            acc1.x += v2.x; acc1.y += v2.y; acc1.z += v2.z; acc1.w += v2.w;
        }
    }

    float* sb = s + b * PC;
    atomicAdd(&sb[tid * 4 + 0], acc0.x);
    atomicAdd(&sb[tid * 4 + 1], acc0.y);
    atomicAdd(&sb[tid * 4 + 2], acc0.z);
    atomicAdd(&sb[tid * 4 + 3], acc0.w);
    if (tid < C4 - 256) {
        atomicAdd(&sb[(256 + tid) * 4 + 0], acc1.x);
        atomicAdd(&sb[(256 + tid) * 4 + 1], acc1.y);
        atomicAdd(&sb[(256 + tid) * 4 + 2], acc1.z);
        atomicAdd(&sb[(256 + tid) * 4 + 3], acc1.w);
    }
}

// Kernel 2: one wave per (o, b) output. Reduce dot(W[o,:], s[b,:]) and sum(W[o,:]).
// grid = (O, B), block = 64.
__global__ __launch_bounds__(64) void proj_kernel(const float* __restrict__ s,
                                                  const float* __restrict__ W,
                                                  const float* __restrict__ bias,
                                                  const int* __restrict__ length,
                                                  float* __restrict__ out) {
    const int o    = blockIdx.x;
    const int b    = blockIdx.y;
    const int lane = threadIdx.x;

    const float* Wo = W + o * PC;
    const float* sb = s + b * PC;

    float dot = 0.f, wsum = 0.f;
#pragma unroll
    for (int c = lane; c < PC; c += 64) {
        float w = Wo[c];
        dot  += w * sb[c];
        wsum += w;
    }

    // Wave-64 butterfly reduction (two values).
#pragma unroll
    for (int off = 32; off > 0; off >>= 1) {
        dot  += __shfl_down(dot,  off);
        wsum += __shfl_down(wsum, off);
    }

    if (lane == 0) {
        float z = dot * (1.0f / 64.0f)
                - 2.0f * (float)PT * wsum
                + (float)PT * bias[o];
        out[b * PO + o] = z / (float)length[b];
    }
}

extern "C" void kernel_launch(void* const* d_in, const int* in_sizes, int n_in,
                              void* d_out, int out_size, void* d_ws, size_t ws_size,
                              hipStream_t stream) {
    const float* x      = (const float*)d_in[0];
    const int*   length = (const int*)d_in[1];
    const float* W      = (const float*)d_in[2];
    const float* bias   = (const float*)d_in[3];
    float*       out    = (float*)d_out;
    float*       s      = (float*)d_ws;   // [B, C] accumulator

    // ws is poisoned to 0xAA before every timed call — zero the accumulator.
    hipMemsetAsync(s, 0, (size_t)PB * PC * sizeof(float), stream);

    dim3 g1(PB, TSPLIT);
    sum_t_kernel<<<g1, 256, 0, stream>>>(x, s);

    dim3 g2(PO, PB);
    proj_kernel<<<g2, 64, 0, stream>>>(s, W, bias, length, out);
}